// Round 1
// baseline (3133.622 us; speedup 1.0000x reference)
//
#include <hip/hip_runtime.h>

#define DEV __device__ __forceinline__
typedef __attribute__((ext_vector_type(8))) short s16x8;
typedef __attribute__((ext_vector_type(4))) float f32x4;
typedef unsigned short u16;

// ---------- constants ----------
#define NB 16      // B
#define TPN 2
#define NODES 8192
#define D 128
#define P 256
#define NPS 32
#define OUT_LEN 12

DEV f32x4 mfma16(s16x8 a, s16x8 b, f32x4 c) {
  return __builtin_amdgcn_mfma_f32_16x16x32_bf16(a, b, c, 0, 0, 0);
}

DEV short f2bf(float f) {
  union { float f; unsigned u; } v; v.f = f;
  unsigned r = v.u + 0x7fffu + ((v.u >> 16) & 1u);
  return (short)(r >> 16);
}

// swizzled LDS addressing: 256B-row and 512B-row buffers, XOR bits 4-6 by row&7
DEV int swz256(int row, int b) { return (row << 8) + (b ^ ((row & 7) << 4)); }
DEV int swz512(int row, int b) { return (row << 9) + (b ^ ((row & 7) << 4)); }

// A-fragment (or B^T-fragment) load from a swizzled 256B-row bf16 buffer.
// lane l: row = mbase + (l&15), k = kbase + (l>>4)*8 .. +8 contiguous
DEV s16x8 ldsA(const char* base, int mbase, int kbase, int lane) {
  int row = mbase + (lane & 15);
  int b = (kbase + ((lane >> 4) << 3)) << 1;
  return *(const s16x8*)(base + swz256(row, b));
}

// load 8 f32, apply LN, pack to bf16
DEV s16x8 ln8(const float* p, float mn, float rs) {
  float4 v0 = *(const float4*)p;
  float4 v1 = *(const float4*)(p + 4);
  s16x8 o;
  o[0] = f2bf((v0.x - mn) * rs); o[1] = f2bf((v0.y - mn) * rs);
  o[2] = f2bf((v0.z - mn) * rs); o[3] = f2bf((v0.w - mn) * rs);
  o[4] = f2bf((v1.x - mn) * rs); o[5] = f2bf((v1.y - mn) * rs);
  o[6] = f2bf((v1.z - mn) * rs); o[7] = f2bf((v1.w - mn) * rs);
  return o;
}

// ---------------- weight prep: f32 [3][K][N] -> bf16 [3][N][K] ----------------
__global__ void k_prep(const float* __restrict__ src, u16* __restrict__ dst, int K, int N) {
  int idx = blockIdx.x * 256 + threadIdx.x;
  int total = 3 * K * N;
  if (idx >= total) return;
  int l = idx / (K * N);
  int r = idx - l * K * N;
  int n = r / K;
  int k = r - n * K;
  dst[idx] = (u16)f2bf(src[l * K * N + k * N + n]);
}

// ---------------- embedding ----------------
// rex[bt][j][d]; block: 16 rows (j) for one bt, 256 threads
__global__ __launch_bounds__(256) void k_embed(
    const float* __restrict__ x, const int* __restrict__ te, const int* __restrict__ reo_all,
    const float* __restrict__ w_st, const float* __restrict__ b_st,
    const float* __restrict__ node_emb, const float* __restrict__ tod_emb,
    const float* __restrict__ dow_emb, float* __restrict__ rex) {
  __shared__ float sx[16][12], s0[16][12], s1[16][12];
  __shared__ int sed[16][2];
  int gid = blockIdx.x;
  int jc = gid & 511, bt = gid >> 9;
  int b = bt >> 1, tt = bt & 1;
  int tid = threadIdx.x;
  int rl = tid >> 4, c = tid & 15;
  int j = jc * 16 + rl;
  int node = reo_all[j];
  if (c < 12) {
    size_t off = ((size_t)(b * 24 + tt * 12 + c)) * NODES + node;
    sx[rl][c] = x[off];
    int t0 = te[off * 2], t1 = te[off * 2 + 1];
    s0[rl][c] = (float)t0 * (1.0f / 288.0f);
    s1[rl][c] = (float)t1 * (1.0f / 7.0f);
  } else if (c == 12) {
    size_t off = ((size_t)(b * 24 + 22 + tt)) * NODES + node;
    sed[rl][0] = te[off * 2];
    sed[rl][1] = te[off * 2 + 1];
  }
  __syncthreads();
  int db = c * 8;
  float o[8];
#pragma unroll
  for (int dd = 0; dd < 8; ++dd) {
    int d = db + dd;
    float v;
    if (d < 64) {
      float acc = b_st[d];
      const float* wd = w_st + d * 36;
#pragma unroll
      for (int p = 0; p < 12; ++p)
        acc += sx[rl][p] * wd[p] + s0[rl][p] * wd[12 + p] + s1[rl][p] * wd[24 + p];
      v = acc;
    } else if (d < 80) {
      v = tod_emb[sed[rl][0] * 16 + (d - 64)];
    } else if (d < 96) {
      v = dow_emb[sed[rl][1] * 16 + (d - 80)];
    } else {
      v = node_emb[node * 32 + (d - 96)];
    }
    o[dd] = v;
  }
  float* dst = rex + ((size_t)bt * NODES + j) * D + db;
  *(float4*)dst = make_float4(o[0], o[1], o[2], o[3]);
  *(float4*)(dst + 4) = make_float4(o[4], o[5], o[6], o[7]);
}

// ---------------- spatial attention: 1 wave per 32-token sequence ----------------
__global__ __launch_bounds__(64) void k_spatial(
    float* __restrict__ rex,
    const u16* __restrict__ wqkv, const float* __restrict__ bqkv,
    const u16* __restrict__ wprj, const float* __restrict__ bprj) {
  __shared__ __align__(16) char sm[26880];
  char* Qb = sm;             // 32 x 256B swz (reused as AV bf16)
  char* Kb = sm + 8192;      // 32 x 256B swz (reused as attn weights a)
  char* VT = sm + 16384;     // 128 rows x 80B (V transposed, padded)
  float* stats = (float*)(sm + 26624);  // 32 x {mean, rstd}
  int lane = threadIdx.x;
  int r = lane & 15, g = lane >> 4;
  float* X = rex + (size_t)blockIdx.x * (NPS * D);

  // LN stats: 2 lanes per row
  {
    int row = lane >> 1, half = lane & 1;
    const float* xr = X + row * D + half * 64;
    float s = 0.f, s2 = 0.f;
#pragma unroll
    for (int i = 0; i < 64; i += 4) {
      float4 v = *(const float4*)(xr + i);
      s += v.x + v.y + v.z + v.w;
      s2 += v.x * v.x + v.y * v.y + v.z * v.z + v.w * v.w;
    }
    s += __shfl_xor(s, 1);
    s2 += __shfl_xor(s2, 1);
    if (!half) {
      float mn = s * 0.0078125f;
      stats[row * 2] = mn;
      stats[row * 2 + 1] = rsqrtf(s2 * 0.0078125f - mn * mn + 1e-6f);
    }
  }
  __syncthreads();

  // LN'd A-fragments in registers
  s16x8 ax[2][4];
#pragma unroll
  for (int mt = 0; mt < 2; ++mt) {
    int row = mt * 16 + r;
    float mn = stats[row * 2], rs = stats[row * 2 + 1];
#pragma unroll
    for (int kt = 0; kt < 4; ++kt)
      ax[mt][kt] = ln8(X + row * D + kt * 32 + g * 8, mn, rs);
  }

  // QKV GEMM (32x384), weights bf16 [n][k]
  for (int nt = 0; nt < 24; ++nt) {
    int n = nt * 16 + r;
    f32x4 a0 = {0.f, 0.f, 0.f, 0.f}, a1 = {0.f, 0.f, 0.f, 0.f};
#pragma unroll
    for (int kt = 0; kt < 4; ++kt) {
      s16x8 b = *(const s16x8*)(wqkv + (size_t)n * D + kt * 32 + g * 8);
      a0 = mfma16(ax[0][kt], b, a0);
      a1 = mfma16(ax[1][kt], b, a1);
    }
    float bias = bqkv[n];
#pragma unroll
    for (int e = 0; e < 4; ++e) {
      float v0 = a0[e] + bias, v1 = a1[e] + bias;
      int t0 = g * 4 + e, t1 = 16 + g * 4 + e;
      if (nt < 8) {
        *(u16*)(Qb + swz256(t0, n * 2)) = (u16)f2bf(v0);
        *(u16*)(Qb + swz256(t1, n * 2)) = (u16)f2bf(v1);
      } else if (nt < 16) {
        int cc = n - 128;
        *(u16*)(Kb + swz256(t0, cc * 2)) = (u16)f2bf(v0);
        *(u16*)(Kb + swz256(t1, cc * 2)) = (u16)f2bf(v1);
      } else {
        int dd = n - 256;
        *(u16*)(VT + dd * 80 + t0 * 2) = (u16)f2bf(v0);
        *(u16*)(VT + dd * 80 + t1 * 2) = (u16)f2bf(v1);
      }
    }
  }
  __syncthreads();

  // scores = Q K^T * scale (2x2 tiles)
  s16x8 aqf[2][4];
#pragma unroll
  for (int mt = 0; mt < 2; ++mt)
#pragma unroll
    for (int kt = 0; kt < 4; ++kt) aqf[mt][kt] = ldsA(Qb, mt * 16, kt * 32, lane);
  const float scale = 0.08838834764831845f;
  f32x4 sc[2][2];
#pragma unroll
  for (int mt = 0; mt < 2; ++mt)
#pragma unroll
    for (int nt2 = 0; nt2 < 2; ++nt2) {
      f32x4 acc = {0.f, 0.f, 0.f, 0.f};
#pragma unroll
      for (int kt = 0; kt < 4; ++kt) {
        s16x8 b = ldsA(Kb, nt2 * 16, kt * 32, lane);
        acc = mfma16(aqf[mt][kt], b, acc);
      }
      sc[mt][nt2] = acc * scale;
    }

  // softmax over 32 cols per row; write a (bf16) into Kb
#pragma unroll
  for (int mt = 0; mt < 2; ++mt) {
#pragma unroll
    for (int e = 0; e < 4; ++e) {
      float v0 = sc[mt][0][e], v1 = sc[mt][1][e];
      float m = fmaxf(v0, v1);
      m = fmaxf(m, __shfl_xor(m, 1));
      m = fmaxf(m, __shfl_xor(m, 2));
      m = fmaxf(m, __shfl_xor(m, 4));
      m = fmaxf(m, __shfl_xor(m, 8));
      float p0 = __expf(v0 - m), p1 = __expf(v1 - m);
      float s = p0 + p1;
      s += __shfl_xor(s, 1);
      s += __shfl_xor(s, 2);
      s += __shfl_xor(s, 4);
      s += __shfl_xor(s, 8);
      float ri = 1.0f / s;
      int row = mt * 16 + g * 4 + e;
      *(u16*)(Kb + swz256(row, r * 2)) = (u16)f2bf(p0 * ri);
      *(u16*)(Kb + swz256(row, (16 + r) * 2)) = (u16)f2bf(p1 * ri);
    }
  }

  // AV (K=32, one MFMA per tile); results to Qb as bf16
#pragma unroll
  for (int mt = 0; mt < 2; ++mt) {
    s16x8 af = ldsA(Kb, mt * 16, 0, lane);
#pragma unroll
    for (int nt = 0; nt < 8; ++nt) {
      s16x8 bv = *(const s16x8*)(VT + (nt * 16 + r) * 80 + g * 16);
      f32x4 acc = {0.f, 0.f, 0.f, 0.f};
      acc = mfma16(af, bv, acc);
#pragma unroll
      for (int e = 0; e < 4; ++e)
        *(u16*)(Qb + swz256(mt * 16 + g * 4 + e, (nt * 16 + r) * 2)) = (u16)f2bf(acc[e]);
    }
  }

  // proj + residual
  s16x8 aav[2][4];
#pragma unroll
  for (int mt = 0; mt < 2; ++mt)
#pragma unroll
    for (int kt = 0; kt < 4; ++kt) aav[mt][kt] = ldsA(Qb, mt * 16, kt * 32, lane);
#pragma unroll
  for (int nt = 0; nt < 8; ++nt) {
    int n = nt * 16 + r;
    f32x4 a0 = {0.f, 0.f, 0.f, 0.f}, a1 = {0.f, 0.f, 0.f, 0.f};
#pragma unroll
    for (int kt = 0; kt < 4; ++kt) {
      s16x8 b = *(const s16x8*)(wprj + (size_t)n * D + kt * 32 + g * 8);
      a0 = mfma16(aav[0][kt], b, a0);
      a1 = mfma16(aav[1][kt], b, a1);
    }
    float bias = bprj[n];
#pragma unroll
    for (int e = 0; e < 4; ++e) {
      X[(g * 4 + e) * D + n] += a0[e] + bias;
      X[(16 + g * 4 + e) * D + n] += a1[e] + bias;
    }
  }
}

// ---------------- MLP (LN -> fc1 -> gelu -> fc2 -> +res): 1 wave per 32 tokens ----------------
__global__ __launch_bounds__(64) void k_mlp(
    float* __restrict__ rex,
    const u16* __restrict__ w1t, const float* __restrict__ b1,
    const u16* __restrict__ w2t, const float* __restrict__ b2) {
  __shared__ __align__(16) char Hs[8192];
  __shared__ float stats[64];
  int lane = threadIdx.x;
  int r = lane & 15, g = lane >> 4;
  float* X = rex + (size_t)blockIdx.x * (32 * D);
  {
    int row = lane >> 1, half = lane & 1;
    const float* xr = X + row * D + half * 64;
    float s = 0.f, s2 = 0.f;
#pragma unroll
    for (int i = 0; i < 64; i += 4) {
      float4 v = *(const float4*)(xr + i);
      s += v.x + v.y + v.z + v.w;
      s2 += v.x * v.x + v.y * v.y + v.z * v.z + v.w * v.w;
    }
    s += __shfl_xor(s, 1);
    s2 += __shfl_xor(s2, 1);
    if (!half) {
      float mn = s * 0.0078125f;
      stats[row * 2] = mn;
      stats[row * 2 + 1] = rsqrtf(s2 * 0.0078125f - mn * mn + 1e-6f);
    }
  }
  __syncthreads();
  s16x8 ax[2][4];
#pragma unroll
  for (int mt = 0; mt < 2; ++mt) {
    int row = mt * 16 + r;
    float mn = stats[row * 2], rs = stats[row * 2 + 1];
#pragma unroll
    for (int kt = 0; kt < 4; ++kt)
      ax[mt][kt] = ln8(X + row * D + kt * 32 + g * 8, mn, rs);
  }
#pragma unroll
  for (int nt = 0; nt < 8; ++nt) {
    int n = nt * 16 + r;
    f32x4 a0 = {0.f, 0.f, 0.f, 0.f}, a1 = {0.f, 0.f, 0.f, 0.f};
#pragma unroll
    for (int kt = 0; kt < 4; ++kt) {
      s16x8 b = *(const s16x8*)(w1t + (size_t)n * D + kt * 32 + g * 8);
      a0 = mfma16(ax[0][kt], b, a0);
      a1 = mfma16(ax[1][kt], b, a1);
    }
    float bias = b1[n];
#pragma unroll
    for (int e = 0; e < 4; ++e) {
      float v0 = a0[e] + bias, v1 = a1[e] + bias;
      v0 = 0.5f * v0 * (1.0f + erff(v0 * 0.70710678118654752f));
      v1 = 0.5f * v1 * (1.0f + erff(v1 * 0.70710678118654752f));
      *(u16*)(Hs + swz256(g * 4 + e, n * 2)) = (u16)f2bf(v0);
      *(u16*)(Hs + swz256(16 + g * 4 + e, n * 2)) = (u16)f2bf(v1);
    }
  }
  __syncthreads();
  s16x8 ah[2][4];
#pragma unroll
  for (int mt = 0; mt < 2; ++mt)
#pragma unroll
    for (int kt = 0; kt < 4; ++kt) ah[mt][kt] = ldsA(Hs, mt * 16, kt * 32, lane);
#pragma unroll
  for (int nt = 0; nt < 8; ++nt) {
    int n = nt * 16 + r;
    f32x4 a0 = {0.f, 0.f, 0.f, 0.f}, a1 = {0.f, 0.f, 0.f, 0.f};
#pragma unroll
    for (int kt = 0; kt < 4; ++kt) {
      s16x8 b = *(const s16x8*)(w2t + (size_t)n * D + kt * 32 + g * 8);
      a0 = mfma16(ah[0][kt], b, a0);
      a1 = mfma16(ah[1][kt], b, a1);
    }
    float bias = b2[n];
#pragma unroll
    for (int e = 0; e < 4; ++e) {
      X[(g * 4 + e) * D + n] += a0[e] + bias;
      X[(16 + g * 4 + e) * D + n] += a1[e] + bias;
    }
  }
}

// ---------------- cross-patch attention: 4 waves per 256-token sequence ----------------
__global__ __launch_bounds__(256) void k_cross(
    float* __restrict__ rex,
    const u16* __restrict__ wqkv, const float* __restrict__ bqkv,
    const u16* __restrict__ wprj, const float* __restrict__ bprj) {
  __shared__ __align__(16) char sm[147456];
  char* Kb = sm;            // 256 x 256B swz
  char* VT = sm + 65536;    // 128 x 512B swz (V transposed)
  int tid = threadIdx.x;
  int w = tid >> 6, lane = tid & 63;
  char* scr = sm + 131072 + w * 4096;  // per-wave 16 x 256B swz scratch
  int r = lane & 15, g = lane >> 4;

  int sq = blockIdx.x;
  int bt = sq >> 5, i = sq & 31;
  float* X0 = rex + (size_t)bt * (NODES * D) + i * D;
  const int TS = NPS * D;  // token stride = 4096 floats

  // per-row LN stats for this wave's 64 tokens (wave-private scratch)
  {
    int tok = w * 64 + lane;
    const float* xr = X0 + (size_t)tok * TS;
    float s = 0.f, s2 = 0.f;
#pragma unroll
    for (int k2 = 0; k2 < D; k2 += 4) {
      float4 v = *(const float4*)(xr + k2);
      s += v.x + v.y + v.z + v.w;
      s2 += v.x * v.x + v.y * v.y + v.z * v.z + v.w * v.w;
    }
    float mn = s * 0.0078125f;
    float rs = rsqrtf(s2 * 0.0078125f - mn * mn + 1e-6f);
    ((float2*)scr)[lane] = make_float2(mn, rs);
  }
  float mn_r[4], rs_r[4];
#pragma unroll
  for (int mt = 0; mt < 4; ++mt) {
    float2 v = ((float2*)scr)[mt * 16 + r];
    mn_r[mt] = v.x;
    rs_r[mt] = v.y;
  }

  // LN'd A-fragments for this wave's 64 tokens
  s16x8 ax[4][4];
#pragma unroll
  for (int mt = 0; mt < 4; ++mt) {
    int tok = w * 64 + mt * 16 + r;
    const float* xr = X0 + (size_t)tok * TS;
#pragma unroll
    for (int kt = 0; kt < 4; ++kt)
      ax[mt][kt] = ln8(xr + kt * 32 + g * 8, mn_r[mt], rs_r[mt]);
  }

  // K,V for this wave's tokens -> shared LDS
  for (int nt = 0; nt < 16; ++nt) {
    int n = 128 + nt * 16 + r;
    f32x4 acc[4];
#pragma unroll
    for (int mt = 0; mt < 4; ++mt) acc[mt] = (f32x4){0.f, 0.f, 0.f, 0.f};
#pragma unroll
    for (int kt = 0; kt < 4; ++kt) {
      s16x8 b = *(const s16x8*)(wqkv + (size_t)n * D + kt * 32 + g * 8);
#pragma unroll
      for (int mt = 0; mt < 4; ++mt) acc[mt] = mfma16(ax[mt][kt], b, acc[mt]);
    }
    float bias = bqkv[n];
#pragma unroll
    for (int mt = 0; mt < 4; ++mt)
#pragma unroll
      for (int e = 0; e < 4; ++e) {
        int tok = w * 64 + mt * 16 + g * 4 + e;
        float v = acc[mt][e] + bias;
        if (nt < 8)
          *(u16*)(Kb + swz256(tok, (nt * 16 + r) * 2)) = (u16)f2bf(v);
        else
          *(u16*)(VT + swz512((nt - 8) * 16 + r, tok * 2)) = (u16)f2bf(v);
      }
  }
  __syncthreads();

  const float scale = 0.08838834764831845f;
#pragma unroll
  for (int mt = 0; mt < 4; ++mt) {
    // Q tile (16 queries) -> scr -> A-frags
    for (int nt = 0; nt < 8; ++nt) {
      int n = nt * 16 + r;
      f32x4 acc = {0.f, 0.f, 0.f, 0.f};
#pragma unroll
      for (int kt = 0; kt < 4; ++kt) {
        s16x8 b = *(const s16x8*)(wqkv + (size_t)n * D + kt * 32 + g * 8);
        acc = mfma16(ax[mt][kt], b, acc);
      }
      float bias = bqkv[n];
#pragma unroll
      for (int e = 0; e < 4; ++e)
        *(u16*)(scr + swz256(g * 4 + e, n * 2)) = (u16)f2bf(acc[e] + bias);
    }
    s16x8 aq[4];
#pragma unroll
    for (int kt = 0; kt < 4; ++kt) aq[kt] = ldsA(scr, 0, kt * 32, lane);

    // scores vs all 256 keys, kept in registers
    f32x4 sc[16];
#pragma unroll
    for (int nt2 = 0; nt2 < 16; ++nt2) {
      f32x4 acc = {0.f, 0.f, 0.f, 0.f};
#pragma unroll
      for (int kt = 0; kt < 4; ++kt) {
        s16x8 b = ldsA(Kb, nt2 * 16, kt * 32, lane);
        acc = mfma16(aq[kt], b, acc);
      }
      sc[nt2] = acc * scale;
    }

    // softmax (rows spread over 16 lanes x 16 reg tiles)
    float rinv[4];
#pragma unroll
    for (int e = 0; e < 4; ++e) {
      float m = sc[0][e];
#pragma unroll
      for (int nt2 = 1; nt2 < 16; ++nt2) m = fmaxf(m, sc[nt2][e]);
      m = fmaxf(m, __shfl_xor(m, 1));
      m = fmaxf(m, __shfl_xor(m, 2));
      m = fmaxf(m, __shfl_xor(m, 4));
      m = fmaxf(m, __shfl_xor(m, 8));
      float s = 0.f;
#pragma unroll
      for (int nt2 = 0; nt2 < 16; ++nt2) {
        float p = __expf(sc[nt2][e] - m);
        sc[nt2][e] = p;
        s += p;
      }
      s += __shfl_xor(s, 1);
      s += __shfl_xor(s, 2);
      s += __shfl_xor(s, 4);
      s += __shfl_xor(s, 8);
      rinv[e] = 1.0f / s;
    }

    // AV in two key-halves through 4KB scratch
    f32x4 av[8];
#pragma unroll
    for (int nt = 0; nt < 8; ++nt) av[nt] = (f32x4){0.f, 0.f, 0.f, 0.f};
#pragma unroll
    for (int h = 0; h < 2; ++h) {
#pragma unroll
      for (int nt2 = 0; nt2 < 8; ++nt2)
#pragma unroll
        for (int e = 0; e < 4; ++e)
          *(u16*)(scr + swz256(g * 4 + e, (nt2 * 16 + r) * 2)) = (u16)f2bf(sc[h * 8 + nt2][e]);
#pragma unroll
      for (int kk = 0; kk < 4; ++kk) {
        s16x8 ap = ldsA(scr, 0, kk * 32, lane);
#pragma unroll
        for (int nt = 0; nt < 8; ++nt) {
          s16x8 bv = *(const s16x8*)(VT + swz512(nt * 16 + r, (h * 128 + kk * 32 + g * 8) * 2));
          av[nt] = mfma16(ap, bv, av[nt]);
        }
      }
    }

    // normalize rows, redistribute via scr, proj + residual
#pragma unroll
    for (int nt = 0; nt < 8; ++nt)
#pragma unroll
      for (int e = 0; e < 4; ++e)
        *(u16*)(scr + swz256(g * 4 + e, (nt * 16 + r) * 2)) = (u16)f2bf(av[nt][e] * rinv[e]);
    s16x8 aav[4];
#pragma unroll
    for (int kt = 0; kt < 4; ++kt) aav[kt] = ldsA(scr, 0, kt * 32, lane);
    for (int nt = 0; nt < 8; ++nt) {
      int n = nt * 16 + r;
      f32x4 acc = {0.f, 0.f, 0.f, 0.f};
#pragma unroll
      for (int kt = 0; kt < 4; ++kt) {
        s16x8 b = *(const s16x8*)(wprj + (size_t)n * D + kt * 32 + g * 8);
        acc = mfma16(aav[kt], b, acc);
      }
      float bias = bprj[n];
#pragma unroll
      for (int e = 0; e < 4; ++e) {
        int tok = w * 64 + mt * 16 + g * 4 + e;
        X0[(size_t)tok * TS + n] += acc[e] + bias;
      }
    }
  }
}

// ---------------- readout ----------------
__global__ __launch_bounds__(256) void k_readout(
    const float* __restrict__ rex, const int* __restrict__ ori_idx,
    const int* __restrict__ reo_idx, const float* __restrict__ w_reg,
    const float* __restrict__ b_reg, float* __restrict__ out) {
  __shared__ float wl[3072];
  for (int i2 = threadIdx.x; i2 < 3072; i2 += 256) wl[i2] = w_reg[i2];
  __syncthreads();
  int b = blockIdx.x >> 7;
  int chunk = blockIdx.x & 127;
  int m = chunk * 64 + (threadIdx.x >> 2);
  int q = threadIdx.x & 3;
  int nOut = ori_idx[m];
  int j = reo_idx[m];
  int t = q >> 1;
  const float* src = rex + ((size_t)(b * 2 + t) * NODES + j) * D + (q & 1) * 64;
  float acc[12] = {0.f, 0.f, 0.f, 0.f, 0.f, 0.f, 0.f, 0.f, 0.f, 0.f, 0.f, 0.f};
#pragma unroll
  for (int k = 0; k < 64; k += 4) {
    float4 v = *(const float4*)(src + k);
#pragma unroll
    for (int o = 0; o < 12; ++o) {
      float4 wv = *(const float4*)(&wl[o * 256 + q * 64 + k]);
      acc[o] += v.x * wv.x + v.y * wv.y + v.z * wv.z + v.w * wv.w;
    }
  }
#pragma unroll
  for (int o = 0; o < 12; ++o) {
    acc[o] += __shfl_xor(acc[o], 1);
    acc[o] += __shfl_xor(acc[o], 2);
  }
  if (q == 0) {
#pragma unroll
    for (int o = 0; o < 12; ++o)
      out[((size_t)b * 12 + o) * NODES + nOut] = acc[o] + b_reg[o];
  }
}

// ---------------- host ----------------
extern "C" void kernel_launch(void* const* d_in, const int* in_sizes, int n_in,
                              void* d_out, int out_size, void* d_ws, size_t ws_size,
                              hipStream_t stream) {
  (void)in_sizes; (void)n_in; (void)out_size;
  const float* x = (const float*)d_in[0];
  const int* te = (const int*)d_in[1];
  const int* reo_all = (const int*)d_in[2];
  const int* ori_parts = (const int*)d_in[3];
  const int* reo_parts = (const int*)d_in[4];
  const float* w_st = (const float*)d_in[5];
  const float* b_st = (const float*)d_in[6];
  const float* node_emb = (const float*)d_in[7];
  const float* tod_emb = (const float*)d_in[8];
  const float* dow_emb = (const float*)d_in[9];
  const float* s_qkv_w = (const float*)d_in[10];
  const float* s_qkv_b = (const float*)d_in[11];
  const float* s_proj_w = (const float*)d_in[12];
  const float* s_proj_b = (const float*)d_in[13];
  const float* s_fc1_w = (const float*)d_in[14];
  const float* s_fc1_b = (const float*)d_in[15];
  const float* s_fc2_w = (const float*)d_in[16];
  const float* s_fc2_b = (const float*)d_in[17];
  const float* n_qkv_w = (const float*)d_in[18];
  const float* n_qkv_b = (const float*)d_in[19];
  const float* n_proj_w = (const float*)d_in[20];
  const float* n_proj_b = (const float*)d_in[21];
  const float* n_fc1_w = (const float*)d_in[22];
  const float* n_fc1_b = (const float*)d_in[23];
  const float* n_fc2_w = (const float*)d_in[24];
  const float* n_fc2_b = (const float*)d_in[25];
  const float* w_reg = (const float*)d_in[26];
  const float* b_reg = (const float*)d_in[27];

  const size_t REX_BYTES = (size_t)NB * TPN * NODES * D * 4;  // 134217728
  if (ws_size < REX_BYTES + 1179648) return;
  float* rex = (float*)d_ws;
  u16* wt = (u16*)((char*)d_ws + REX_BYTES);
  u16* s_qkv_t = wt + 0;
  u16* s_prj_t = wt + 147456;
  u16* s_fc1_t = wt + 196608;
  u16* s_fc2_t = wt + 245760;
  u16* n_qkv_t = wt + 294912;
  u16* n_prj_t = wt + 442368;
  u16* n_fc1_t = wt + 491520;
  u16* n_fc2_t = wt + 540672;

  k_prep<<<(3 * 128 * 384 + 255) / 256, 256, 0, stream>>>(s_qkv_w, s_qkv_t, 128, 384);
  k_prep<<<(3 * 128 * 128 + 255) / 256, 256, 0, stream>>>(s_proj_w, s_prj_t, 128, 128);
  k_prep<<<(3 * 128 * 128 + 255) / 256, 256, 0, stream>>>(s_fc1_w, s_fc1_t, 128, 128);
  k_prep<<<(3 * 128 * 128 + 255) / 256, 256, 0, stream>>>(s_fc2_w, s_fc2_t, 128, 128);
  k_prep<<<(3 * 128 * 384 + 255) / 256, 256, 0, stream>>>(n_qkv_w, n_qkv_t, 128, 384);
  k_prep<<<(3 * 128 * 128 + 255) / 256, 256, 0, stream>>>(n_proj_w, n_prj_t, 128, 128);
  k_prep<<<(3 * 128 * 128 + 255) / 256, 256, 0, stream>>>(n_fc1_w, n_fc1_t, 128, 128);
  k_prep<<<(3 * 128 * 128 + 255) / 256, 256, 0, stream>>>(n_fc2_w, n_fc2_t, 128, 128);

  k_embed<<<NB * TPN * (NODES / 16), 256, 0, stream>>>(
      x, te, reo_all, w_st, b_st, node_emb, tod_emb, dow_emb, rex);

  for (int l = 0; l < 3; ++l) {
    k_spatial<<<NB * TPN * P, 64, 0, stream>>>(
        rex, s_qkv_t + (size_t)l * 49152, s_qkv_b + l * 384,
        s_prj_t + (size_t)l * 16384, s_proj_b + l * 128);
    k_mlp<<<NB * TPN * P, 64, 0, stream>>>(
        rex, s_fc1_t + (size_t)l * 16384, s_fc1_b + l * 128,
        s_fc2_t + (size_t)l * 16384, s_fc2_b + l * 128);
    k_cross<<<NB * TPN * NPS, 256, 0, stream>>>(
        rex, n_qkv_t + (size_t)l * 49152, n_qkv_b + l * 384,
        n_prj_t + (size_t)l * 16384, n_proj_b + l * 128);
    k_mlp<<<NB * TPN * P, 64, 0, stream>>>(
        rex, n_fc1_t + (size_t)l * 16384, n_fc1_b + l * 128,
        n_fc2_t + (size_t)l * 16384, n_fc2_b + l * 128);
  }

  k_readout<<<NB * (NODES / 64), 256, 0, stream>>>(
      rex, ori_parts, reo_parts, w_reg, b_reg, (float*)d_out);
}